// Round 1
// baseline (668.131 us; speedup 1.0000x reference)
//
#include <hip/hip_runtime.h>
#include <hip/hip_bf16.h>

#define N_NODES 100000
#define DFEAT 128
#define SCAN_BLOCKS 391   // ceil(100000/256)

// ---------------- ws layout (4-byte units) ----------------
// cnt    [0      , 100000)
// cursor [100000 , 200000)
// offs   [200000 , 300096)
// partial[300096 , 300608)
// esrc   [300608 , 1900608)
// agg(f) [1900608, 14700608)   (~58.8 MB total)
#define WS_CNT     0
#define WS_CURSOR  100000
#define WS_OFFS    200000
#define WS_PARTIAL 300096
#define WS_ESRC    300608
#define WS_AGG     1900608

__global__ void hist_kernel(const int* __restrict__ dst, int* __restrict__ cnt, int E) {
    int e = blockIdx.x * blockDim.x + threadIdx.x;
    if (e < E) atomicAdd(&cnt[dst[e]], 1);
}

__global__ void scan1_kernel(const int* __restrict__ cnt, int* __restrict__ offs,
                             int* __restrict__ partial, int n) {
    __shared__ int s[256];
    int i = blockIdx.x * 256 + threadIdx.x;
    int v = (i < n) ? cnt[i] : 0;
    s[threadIdx.x] = v;
    __syncthreads();
    for (int d = 1; d < 256; d <<= 1) {
        int t = (threadIdx.x >= d) ? s[threadIdx.x - d] : 0;
        __syncthreads();
        s[threadIdx.x] += t;
        __syncthreads();
    }
    int incl = s[threadIdx.x];
    if (i < n) offs[i] = incl - v;              // exclusive
    if (threadIdx.x == 255) partial[blockIdx.x] = incl;  // block total
}

__global__ void scan2_kernel(int* __restrict__ partial, int nb) {
    __shared__ int s[512];
    int t = threadIdx.x;
    int v = (t < nb) ? partial[t] : 0;
    s[t] = v;
    __syncthreads();
    for (int d = 1; d < 512; d <<= 1) {
        int u = (t >= d) ? s[t - d] : 0;
        __syncthreads();
        s[t] += u;
        __syncthreads();
    }
    if (t < nb) partial[t] = s[t] - v;          // exclusive
}

__global__ void scan3_kernel(int* __restrict__ offs, const int* __restrict__ partial, int n) {
    int i = blockIdx.x * 256 + threadIdx.x;
    if (i < n) offs[i] += partial[blockIdx.x];
}

__global__ void scatter_kernel(const int* __restrict__ src, const int* __restrict__ dst,
                               const int* __restrict__ offs, int* __restrict__ cursor,
                               int* __restrict__ esrc, int E) {
    int e = blockIdx.x * blockDim.x + threadIdx.x;
    if (e >= E) return;
    int d = dst[e];
    int pos = atomicAdd(&cursor[d], 1);
    esrc[offs[d] + pos] = src[e];
}

// one wave (64 lanes) per node; lane handles 2 contiguous features (float2)
__global__ void aggregate_kernel(const float* __restrict__ feat, const int* __restrict__ esrc,
                                 const int* __restrict__ offs, const int* __restrict__ cnt,
                                 float* __restrict__ agg, int n) {
    int wid = (blockIdx.x * blockDim.x + threadIdx.x) >> 6;
    int lane = threadIdx.x & 63;
    if (wid >= n) return;
    int beg = offs[wid];
    int deg = cnt[wid];
    int col = lane * 2;
    float ax = 0.f, ay = 0.f;
    int j = 0;
    for (; j + 3 < deg; j += 4) {
        int s0 = esrc[beg + j];
        int s1 = esrc[beg + j + 1];
        int s2 = esrc[beg + j + 2];
        int s3 = esrc[beg + j + 3];
        float2 v0 = *(const float2*)(feat + (size_t)s0 * DFEAT + col);
        float2 v1 = *(const float2*)(feat + (size_t)s1 * DFEAT + col);
        float2 v2 = *(const float2*)(feat + (size_t)s2 * DFEAT + col);
        float2 v3 = *(const float2*)(feat + (size_t)s3 * DFEAT + col);
        ax += v0.x + v1.x + v2.x + v3.x;
        ay += v0.y + v1.y + v2.y + v3.y;
    }
    for (; j < deg; j++) {
        int s = esrc[beg + j];
        float2 v = *(const float2*)(feat + (size_t)s * DFEAT + col);
        ax += v.x;
        ay += v.y;
    }
    float scale = 1.0f / fmaxf((float)deg, 1.0f);
    float2 out;
    out.x = ax * scale;
    out.y = ay * scale;
    *(float2*)(agg + (size_t)wid * DFEAT + col) = out;
}

// Fused dual-GEMM: out[i][j] = sum_k A1[i][k]*Wl[j][k] + sum_k A2[i][k]*Wr[j][k] + b[j]
// Block tile: 64 nodes x 128 features. 256 threads; thread = 8 nodes x 4 features.
// Layer 1: + L2-normalize row (eps=1e-12) + ReLU.
template <bool NORM_RELU>
__global__ __launch_bounds__(256) void gemm_fused_kernel(
    const float* __restrict__ A1, const float* __restrict__ A2,
    const float* __restrict__ Wl, const float* __restrict__ Wr,
    const float* __restrict__ bias, float* __restrict__ out, int n) {
    __shared__ float As[32][68];    // padded: 68*4=272B rows (16B aligned, bank-staggered)
    __shared__ float Ws[32][132];   // padded: 132*4=528B rows

    const int t = threadIdx.x;
    const int g = t >> 5;   // 0..7  (node group)
    const int l = t & 31;   // 0..31 (feature group: features l*4..l*4+3)
    const int i0 = blockIdx.x * 64;

    float acc[8][4] = {};

    for (int half = 0; half < 2; half++) {
        const float* __restrict__ A = half ? A2 : A1;
        const float* __restrict__ W = half ? Wr : Wl;
        for (int kc = 0; kc < DFEAT; kc += 32) {
            // stage A chunk: 64 rows x 32 k -> As[k][row] (transposed)
#pragma unroll
            for (int rep = 0; rep < 2; rep++) {
                int f4 = t + rep * 256;          // 0..511
                int row = f4 >> 3;               // 0..63
                int kk = (f4 & 7) * 4;           // 0..28
                int gi = i0 + row;
                if (gi >= n) gi = n - 1;         // clamp (stores guarded)
                float4 v = *(const float4*)(A + (size_t)gi * DFEAT + kc + kk);
                As[kk + 0][row] = v.x;
                As[kk + 1][row] = v.y;
                As[kk + 2][row] = v.z;
                As[kk + 3][row] = v.w;
            }
            // stage W chunk: 128 rows(j) x 32 k -> Ws[k][j]
#pragma unroll
            for (int rep = 0; rep < 4; rep++) {
                int f4 = t + rep * 256;          // 0..1023
                int jj = f4 >> 3;                // 0..127
                int kk = (f4 & 7) * 4;
                float4 v = *(const float4*)(W + jj * DFEAT + kc + kk);
                Ws[kk + 0][jj] = v.x;
                Ws[kk + 1][jj] = v.y;
                Ws[kk + 2][jj] = v.z;
                Ws[kk + 3][jj] = v.w;
            }
            __syncthreads();
#pragma unroll
            for (int k = 0; k < 32; k++) {
                float4 a03 = *(const float4*)&As[k][g * 8];      // broadcast
                float4 a47 = *(const float4*)&As[k][g * 8 + 4];  // broadcast
                float4 w = *(const float4*)&Ws[k][l * 4];
                float av[8] = {a03.x, a03.y, a03.z, a03.w, a47.x, a47.y, a47.z, a47.w};
                float wv[4] = {w.x, w.y, w.z, w.w};
#pragma unroll
                for (int r = 0; r < 8; r++)
#pragma unroll
                    for (int c = 0; c < 4; c++)
                        acc[r][c] = fmaf(av[r], wv[c], acc[r][c]);
            }
            __syncthreads();
        }
    }

    const float4 bv = *(const float4*)&bias[l * 4];
#pragma unroll
    for (int r = 0; r < 8; r++) {
        float v0 = acc[r][0] + bv.x;
        float v1 = acc[r][1] + bv.y;
        float v2 = acc[r][2] + bv.z;
        float v3 = acc[r][3] + bv.w;
        if (NORM_RELU) {
            float ss = v0 * v0 + v1 * v1 + v2 * v2 + v3 * v3;
            ss += __shfl_xor(ss, 1);
            ss += __shfl_xor(ss, 2);
            ss += __shfl_xor(ss, 4);
            ss += __shfl_xor(ss, 8);
            ss += __shfl_xor(ss, 16);
            float inv = 1.0f / fmaxf(sqrtf(ss), 1e-12f);
            v0 = fmaxf(v0 * inv, 0.0f);
            v1 = fmaxf(v1 * inv, 0.0f);
            v2 = fmaxf(v2 * inv, 0.0f);
            v3 = fmaxf(v3 * inv, 0.0f);
        }
        int row = i0 + g * 8 + r;
        if (row < n) {
            *(float4*)(out + (size_t)row * DFEAT + l * 4) = make_float4(v0, v1, v2, v3);
        }
    }
}

extern "C" void kernel_launch(void* const* d_in, const int* in_sizes, int n_in,
                              void* d_out, int out_size, void* d_ws, size_t ws_size,
                              hipStream_t stream) {
    const float* x = (const float*)d_in[0];
    const int* edge_index = (const int*)d_in[1];  // harness materializes ints as int32
    const float* W1l = (const float*)d_in[2];
    const float* b1 = (const float*)d_in[3];
    const float* W1r = (const float*)d_in[4];
    const float* W2l = (const float*)d_in[5];
    const float* b2 = (const float*)d_in[6];
    const float* W2r = (const float*)d_in[7];
    float* out = (float*)d_out;

    const int E = in_sizes[1] / 2;
    const int n = in_sizes[0] / DFEAT;  // 100000

    int* ws = (int*)d_ws;
    int* cnt = ws + WS_CNT;
    int* cursor = ws + WS_CURSOR;
    int* offs = ws + WS_OFFS;
    int* partial = ws + WS_PARTIAL;
    int* esrc = ws + WS_ESRC;
    float* agg = (float*)(ws + WS_AGG);

    const int* src = edge_index;
    const int* dst = edge_index + E;

    // zero cnt + cursor (contiguous)
    hipMemsetAsync(cnt, 0, (size_t)2 * N_NODES * sizeof(int), stream);

    const int eb = (E + 255) / 256;
    hist_kernel<<<eb, 256, 0, stream>>>(dst, cnt, E);
    scan1_kernel<<<SCAN_BLOCKS, 256, 0, stream>>>(cnt, offs, partial, n);
    scan2_kernel<<<1, 512, 0, stream>>>(partial, SCAN_BLOCKS);
    scan3_kernel<<<SCAN_BLOCKS, 256, 0, stream>>>(offs, partial, n);
    scatter_kernel<<<eb, 256, 0, stream>>>(src, dst, offs, cursor, esrc, E);

    const int aggb = (n * 64 + 255) / 256;  // one wave per node
    const int gemmb = (n + 63) / 64;

    // layer 1: agg(x) -> h = relu(normalize(agg@W1l^T + b1 + x@W1r^T)); h staged in d_out
    aggregate_kernel<<<aggb, 256, 0, stream>>>(x, esrc, offs, cnt, agg, n);
    gemm_fused_kernel<true><<<gemmb, 256, 0, stream>>>(agg, x, W1l, W1r, b1, out, n);

    // layer 2: agg(h) -> out = agg@W2l^T + b2 + h@W2r^T (in-place safe: row-wise)
    aggregate_kernel<<<aggb, 256, 0, stream>>>(out, esrc, offs, cnt, agg, n);
    gemm_fused_kernel<false><<<gemmb, 256, 0, stream>>>(agg, out, W2l, W2r, b2, out, n);
}

// Round 2
// 628.497 us; speedup vs baseline: 1.0631x; 1.0631x over previous
//
#include <hip/hip_runtime.h>
#include <hip/hip_bf16.h>
#include <hip/hip_fp16.h>

#define N_NODES 100000
#define DFEAT 128
#define SCAN_BLOCKS 391   // ceil(100000/256)

// ---------------- ws layout (4-byte units) ----------------
// cnt    [0      , 100000)
// cursor [100000 , 200000)
// offs   [200000 , 300096)
// partial[300096 , 300608)
// esrc   [300608 , 1900608)
// aggh   [1900608, 8300608)    fp16 100000x128 (25.6 MB)
// casth  [8300608, 14700608)   fp16 100000x128 (25.6 MB) — x_fp16, then h_fp16
// total 58.8 MB (same footprint as round 1)
#define WS_CNT     0
#define WS_CURSOR  100000
#define WS_OFFS    200000
#define WS_PARTIAL 300096
#define WS_ESRC    300608
#define WS_AGGH    1900608
#define WS_CASTH   8300608

__global__ void hist_kernel(const int* __restrict__ dst, int* __restrict__ cnt, int E) {
    int e = blockIdx.x * blockDim.x + threadIdx.x;
    if (e < E) atomicAdd(&cnt[dst[e]], 1);
}

__global__ void scan1_kernel(const int* __restrict__ cnt, int* __restrict__ offs,
                             int* __restrict__ partial, int n) {
    __shared__ int s[256];
    int i = blockIdx.x * 256 + threadIdx.x;
    int v = (i < n) ? cnt[i] : 0;
    s[threadIdx.x] = v;
    __syncthreads();
    for (int d = 1; d < 256; d <<= 1) {
        int t = (threadIdx.x >= d) ? s[threadIdx.x - d] : 0;
        __syncthreads();
        s[threadIdx.x] += t;
        __syncthreads();
    }
    int incl = s[threadIdx.x];
    if (i < n) offs[i] = incl - v;              // exclusive
    if (threadIdx.x == 255) partial[blockIdx.x] = incl;  // block total
}

__global__ void scan2_kernel(int* __restrict__ partial, int nb) {
    __shared__ int s[512];
    int t = threadIdx.x;
    int v = (t < nb) ? partial[t] : 0;
    s[t] = v;
    __syncthreads();
    for (int d = 1; d < 512; d <<= 1) {
        int u = (t >= d) ? s[t - d] : 0;
        __syncthreads();
        s[t] += u;
        __syncthreads();
    }
    if (t < nb) partial[t] = s[t] - v;          // exclusive
}

__global__ void scan3_kernel(int* __restrict__ offs, const int* __restrict__ partial, int n) {
    int i = blockIdx.x * 256 + threadIdx.x;
    if (i < n) offs[i] += partial[blockIdx.x];
}

__global__ void scatter_kernel(const int* __restrict__ src, const int* __restrict__ dst,
                               const int* __restrict__ offs, int* __restrict__ cursor,
                               int* __restrict__ esrc, int E) {
    int e = blockIdx.x * blockDim.x + threadIdx.x;
    if (e >= E) return;
    int d = dst[e];
    int pos = atomicAdd(&cursor[d], 1);
    esrc[offs[d] + pos] = src[e];
}

// fp32 -> fp16 cast, 4 elements/thread
__global__ void cast_kernel(const float* __restrict__ x, __half* __restrict__ xh, int total4) {
    int i = blockIdx.x * blockDim.x + threadIdx.x;
    if (i >= total4) return;
    float4 v = ((const float4*)x)[i];
    __half2 h01 = __floats2half2_rn(v.x, v.y);
    __half2 h23 = __floats2half2_rn(v.z, v.w);
    uint2 o;
    o.x = *(unsigned int*)&h01;
    o.y = *(unsigned int*)&h23;
    ((uint2*)xh)[i] = o;
}

// one wave per node. Pair mode: lanes 0..31 handle edge j, lanes 32..63 edge j+1;
// each lane loads 8 B (4 fp16) -> 512 B per load instruction across the wave.
// fp32 accumulate, fp16 output.
__global__ void aggregate_kernel(const __half* __restrict__ feat, const int* __restrict__ esrc,
                                 const int* __restrict__ offs, const int* __restrict__ cnt,
                                 __half* __restrict__ agg, int n) {
    int wid = (blockIdx.x * blockDim.x + threadIdx.x) >> 6;
    int lane = threadIdx.x & 63;
    if (wid >= n) return;
    int beg = offs[wid];
    int deg = cnt[wid];
    int half_id = lane >> 5;     // 0 or 1: which edge of the pair
    int colbase = (lane & 31) * 4;
    float a0 = 0.f, a1 = 0.f, a2 = 0.f, a3 = 0.f;

    for (int base = 0; base < deg; base += 64) {
        int m = min(64, deg - base);
        int idx = (lane < m) ? esrc[beg + base + lane] : 0;
#pragma unroll 4
        for (int j = 0; j < m; j += 2) {
            int jj = j + half_id;
            bool valid = jj < m;
            int s = __shfl(idx, valid ? jj : (m - 1));
            uint2 raw = *(const uint2*)(feat + (size_t)s * DFEAT + colbase);
            __half2 h01 = *(__half2*)&raw.x;
            __half2 h23 = *(__half2*)&raw.y;
            float2 f01 = __half22float2(h01);
            float2 f23 = __half22float2(h23);
            float w = valid ? 1.0f : 0.0f;
            a0 = fmaf(w, f01.x, a0);
            a1 = fmaf(w, f01.y, a1);
            a2 = fmaf(w, f23.x, a2);
            a3 = fmaf(w, f23.y, a3);
        }
    }
    // combine the two edge-parity partials (lane L and L+32 hold same columns)
    a0 += __shfl_xor(a0, 32);
    a1 += __shfl_xor(a1, 32);
    a2 += __shfl_xor(a2, 32);
    a3 += __shfl_xor(a3, 32);

    if (lane < 32) {
        float scale = 1.0f / fmaxf((float)deg, 1.0f);
        __half2 h01 = __floats2half2_rn(a0 * scale, a1 * scale);
        __half2 h23 = __floats2half2_rn(a2 * scale, a3 * scale);
        uint2 o;
        o.x = *(unsigned int*)&h01;
        o.y = *(unsigned int*)&h23;
        *(uint2*)(agg + (size_t)wid * DFEAT + colbase) = o;
    }
}

// Fused dual-GEMM: out[i][j] = sum_k A1[i][k]*Wl[j][k] + sum_k A2[i][k]*Wr[j][k] + b[j]
// A1 is fp16 (aggregate), A2 is fp32 (root features).
// Block tile: 64 nodes x 128 features. 256 threads; thread = 8 nodes x 4 features.
// NORM_RELU (layer 1): L2-normalize row + ReLU, and also emit fp16 copy to out_h.
template <bool NORM_RELU>
__global__ __launch_bounds__(256) void gemm_fused_kernel(
    const __half* __restrict__ A1, const float* __restrict__ A2,
    const float* __restrict__ Wl, const float* __restrict__ Wr,
    const float* __restrict__ bias, float* __restrict__ out,
    __half* __restrict__ out_h, int n) {
    __shared__ float As[32][68];    // padded
    __shared__ float Ws[32][132];   // padded

    const int t = threadIdx.x;
    const int g = t >> 5;   // 0..7  (node group)
    const int l = t & 31;   // 0..31 (feature group: features l*4..l*4+3)
    const int i0 = blockIdx.x * 64;

    float acc[8][4] = {};

    for (int half = 0; half < 2; half++) {
        const float* __restrict__ W = half ? Wr : Wl;
        for (int kc = 0; kc < DFEAT; kc += 32) {
            // stage A chunk: 64 rows x 32 k -> As[k][row] (transposed)
#pragma unroll
            for (int rep = 0; rep < 2; rep++) {
                int f4 = t + rep * 256;          // 0..511
                int row = f4 >> 3;               // 0..63
                int kk = (f4 & 7) * 4;           // 0..28
                int gi = i0 + row;
                if (gi >= n) gi = n - 1;         // clamp (stores guarded)
                if (half == 0) {
                    uint2 raw = *(const uint2*)(A1 + (size_t)gi * DFEAT + kc + kk);
                    float2 f01 = __half22float2(*(__half2*)&raw.x);
                    float2 f23 = __half22float2(*(__half2*)&raw.y);
                    As[kk + 0][row] = f01.x;
                    As[kk + 1][row] = f01.y;
                    As[kk + 2][row] = f23.x;
                    As[kk + 3][row] = f23.y;
                } else {
                    float4 v = *(const float4*)(A2 + (size_t)gi * DFEAT + kc + kk);
                    As[kk + 0][row] = v.x;
                    As[kk + 1][row] = v.y;
                    As[kk + 2][row] = v.z;
                    As[kk + 3][row] = v.w;
                }
            }
            // stage W chunk: 128 rows(j) x 32 k -> Ws[k][j]
#pragma unroll
            for (int rep = 0; rep < 4; rep++) {
                int f4 = t + rep * 256;          // 0..1023
                int jj = f4 >> 3;                // 0..127
                int kk = (f4 & 7) * 4;
                float4 v = *(const float4*)(W + jj * DFEAT + kc + kk);
                Ws[kk + 0][jj] = v.x;
                Ws[kk + 1][jj] = v.y;
                Ws[kk + 2][jj] = v.z;
                Ws[kk + 3][jj] = v.w;
            }
            __syncthreads();
#pragma unroll
            for (int k = 0; k < 32; k++) {
                float4 a03 = *(const float4*)&As[k][g * 8];      // broadcast
                float4 a47 = *(const float4*)&As[k][g * 8 + 4];  // broadcast
                float4 w = *(const float4*)&Ws[k][l * 4];
                float av[8] = {a03.x, a03.y, a03.z, a03.w, a47.x, a47.y, a47.z, a47.w};
                float wv[4] = {w.x, w.y, w.z, w.w};
#pragma unroll
                for (int r = 0; r < 8; r++)
#pragma unroll
                    for (int c = 0; c < 4; c++)
                        acc[r][c] = fmaf(av[r], wv[c], acc[r][c]);
            }
            __syncthreads();
        }
    }

    const float4 bv = *(const float4*)&bias[l * 4];
#pragma unroll
    for (int r = 0; r < 8; r++) {
        float v0 = acc[r][0] + bv.x;
        float v1 = acc[r][1] + bv.y;
        float v2 = acc[r][2] + bv.z;
        float v3 = acc[r][3] + bv.w;
        if (NORM_RELU) {
            float ss = v0 * v0 + v1 * v1 + v2 * v2 + v3 * v3;
            ss += __shfl_xor(ss, 1);
            ss += __shfl_xor(ss, 2);
            ss += __shfl_xor(ss, 4);
            ss += __shfl_xor(ss, 8);
            ss += __shfl_xor(ss, 16);
            float inv = 1.0f / fmaxf(sqrtf(ss), 1e-12f);
            v0 = fmaxf(v0 * inv, 0.0f);
            v1 = fmaxf(v1 * inv, 0.0f);
            v2 = fmaxf(v2 * inv, 0.0f);
            v3 = fmaxf(v3 * inv, 0.0f);
        }
        int row = i0 + g * 8 + r;
        if (row < n) {
            *(float4*)(out + (size_t)row * DFEAT + l * 4) = make_float4(v0, v1, v2, v3);
            if (NORM_RELU) {
                __half2 h01 = __floats2half2_rn(v0, v1);
                __half2 h23 = __floats2half2_rn(v2, v3);
                uint2 o;
                o.x = *(unsigned int*)&h01;
                o.y = *(unsigned int*)&h23;
                *(uint2*)(out_h + (size_t)row * DFEAT + l * 4) = o;
            }
        }
    }
}

extern "C" void kernel_launch(void* const* d_in, const int* in_sizes, int n_in,
                              void* d_out, int out_size, void* d_ws, size_t ws_size,
                              hipStream_t stream) {
    const float* x = (const float*)d_in[0];
    const int* edge_index = (const int*)d_in[1];
    const float* W1l = (const float*)d_in[2];
    const float* b1 = (const float*)d_in[3];
    const float* W1r = (const float*)d_in[4];
    const float* W2l = (const float*)d_in[5];
    const float* b2 = (const float*)d_in[6];
    const float* W2r = (const float*)d_in[7];
    float* out = (float*)d_out;

    const int E = in_sizes[1] / 2;
    const int n = in_sizes[0] / DFEAT;  // 100000

    int* ws = (int*)d_ws;
    int* cnt = ws + WS_CNT;
    int* cursor = ws + WS_CURSOR;
    int* offs = ws + WS_OFFS;
    int* partial = ws + WS_PARTIAL;
    int* esrc = ws + WS_ESRC;
    __half* aggh = (__half*)(ws + WS_AGGH);
    __half* casth = (__half*)(ws + WS_CASTH);

    const int* src = edge_index;
    const int* dst = edge_index + E;

    // zero cnt + cursor (contiguous)
    hipMemsetAsync(cnt, 0, (size_t)2 * N_NODES * sizeof(int), stream);

    const int eb = (E + 255) / 256;
    hist_kernel<<<eb, 256, 0, stream>>>(dst, cnt, E);
    scan1_kernel<<<SCAN_BLOCKS, 256, 0, stream>>>(cnt, offs, partial, n);
    scan2_kernel<<<1, 512, 0, stream>>>(partial, SCAN_BLOCKS);
    scan3_kernel<<<SCAN_BLOCKS, 256, 0, stream>>>(offs, partial, n);
    scatter_kernel<<<eb, 256, 0, stream>>>(src, dst, offs, cursor, esrc, E);

    const int total4 = n * DFEAT / 4;
    cast_kernel<<<(total4 + 255) / 256, 256, 0, stream>>>(x, casth, total4);

    const int aggb = (n * 64 + 255) / 256;  // one wave per node
    const int gemmb = (n + 63) / 64;

    // layer 1: agg(x_h) -> aggh; h = relu(normalize(aggh@W1l^T + b1 + x@W1r^T))
    // h written fp32 to d_out and fp16 to casth (reused)
    aggregate_kernel<<<aggb, 256, 0, stream>>>(casth, esrc, offs, cnt, aggh, n);
    gemm_fused_kernel<true><<<gemmb, 256, 0, stream>>>(aggh, x, W1l, W1r, b1, out, casth, n);

    // layer 2: agg(h_h) -> aggh; out = aggh@W2l^T + b2 + h@W2r^T (in-place safe: row-wise)
    aggregate_kernel<<<aggb, 256, 0, stream>>>(casth, esrc, offs, cnt, aggh, n);
    gemm_fused_kernel<false><<<gemmb, 256, 0, stream>>>(aggh, out, W2l, W2r, b2, out, nullptr, n);
}

// Round 3
// 517.353 us; speedup vs baseline: 1.2914x; 1.2148x over previous
//
#include <hip/hip_runtime.h>
#include <hip/hip_bf16.h>
#include <hip/hip_fp16.h>

#define N_NODES 100000
#define DFEAT 128
#define SCAN_BLOCKS 391   // ceil(100000/256)

// ---------------- ws layout (4-byte units) ----------------
// cnt    [0      , 100000)
// cursor [100000 , 200000)   -- reused as fp16 weights (65536 halves) after scatter
// offs   [200000 , 300096)
// partial[300096 , 300608)
// esrc   [300608 , 1900608)
// aggh   [1900608, 8300608)    fp16 100000x128 (25.6 MB): agg1, then h
// casth  [8300608, 14700608)   fp16 100000x128 (25.6 MB): x_h, then agg2
#define WS_CNT     0
#define WS_CURSOR  100000
#define WS_OFFS    200000
#define WS_PARTIAL 300096
#define WS_ESRC    300608
#define WS_AGGH    1900608
#define WS_CASTH   8300608

typedef _Float16 half8 __attribute__((ext_vector_type(8)));
typedef _Float16 half4v __attribute__((ext_vector_type(4)));
typedef float floatx4 __attribute__((ext_vector_type(4)));

__global__ void hist_kernel(const int* __restrict__ dst, int* __restrict__ cnt, int E) {
    int e = blockIdx.x * blockDim.x + threadIdx.x;
    if (e < E) atomicAdd(&cnt[dst[e]], 1);
}

__global__ void scan1_kernel(const int* __restrict__ cnt, int* __restrict__ offs,
                             int* __restrict__ partial, int n) {
    __shared__ int s[256];
    int i = blockIdx.x * 256 + threadIdx.x;
    int v = (i < n) ? cnt[i] : 0;
    s[threadIdx.x] = v;
    __syncthreads();
    for (int d = 1; d < 256; d <<= 1) {
        int t = (threadIdx.x >= d) ? s[threadIdx.x - d] : 0;
        __syncthreads();
        s[threadIdx.x] += t;
        __syncthreads();
    }
    int incl = s[threadIdx.x];
    if (i < n) offs[i] = incl - v;              // exclusive
    if (threadIdx.x == 255) partial[blockIdx.x] = incl;  // block total
}

__global__ void scan2_kernel(int* __restrict__ partial, int nb) {
    __shared__ int s[512];
    int t = threadIdx.x;
    int v = (t < nb) ? partial[t] : 0;
    s[t] = v;
    __syncthreads();
    for (int d = 1; d < 512; d <<= 1) {
        int u = (t >= d) ? s[t - d] : 0;
        __syncthreads();
        s[t] += u;
        __syncthreads();
    }
    if (t < nb) partial[t] = s[t] - v;          // exclusive
}

__global__ void scan3_kernel(int* __restrict__ offs, const int* __restrict__ partial, int n) {
    int i = blockIdx.x * 256 + threadIdx.x;
    if (i < n) offs[i] += partial[blockIdx.x];
}

__global__ void scatter_kernel(const int* __restrict__ src, const int* __restrict__ dst,
                               const int* __restrict__ offs, int* __restrict__ cursor,
                               int* __restrict__ esrc, int E) {
    int e = blockIdx.x * blockDim.x + threadIdx.x;
    if (e >= E) return;
    int d = dst[e];
    int pos = atomicAdd(&cursor[d], 1);
    esrc[offs[d] + pos] = src[e];
}

// fp32 -> fp16 cast, 4 elements/thread
__global__ void cast_kernel(const float* __restrict__ x, __half* __restrict__ xh, int total4) {
    int i = blockIdx.x * blockDim.x + threadIdx.x;
    if (i >= total4) return;
    float4 v = ((const float4*)x)[i];
    __half2 h01 = __floats2half2_rn(v.x, v.y);
    __half2 h23 = __floats2half2_rn(v.z, v.w);
    uint2 o;
    o.x = *(unsigned int*)&h01;
    o.y = *(unsigned int*)&h23;
    ((uint2*)xh)[i] = o;
}

// cast 4 weight matrices (128x128 fp32) to fp16, packed [W1l|W1r|W2l|W2r]
__global__ void cast_w_kernel(const float* __restrict__ W1l, const float* __restrict__ W1r,
                              const float* __restrict__ W2l, const float* __restrict__ W2r,
                              __half* __restrict__ wh) {
    int i = blockIdx.x * blockDim.x + threadIdx.x;  // 0..16383 (x4 elems)
    if (i >= 16384) return;
    const float* srcs[4] = {W1l, W1r, W2l, W2r};
    int m = i >> 12;                 // 4096 threads per matrix
    int j = (i & 4095) * 4;
    float4 v = *(const float4*)(srcs[m] + j);
    __half2 h01 = __floats2half2_rn(v.x, v.y);
    __half2 h23 = __floats2half2_rn(v.z, v.w);
    uint2 o;
    o.x = *(unsigned int*)&h01;
    o.y = *(unsigned int*)&h23;
    *(uint2*)(wh + m * 16384 + j) = o;
}

// one wave per node. Pair mode: lanes 0..31 handle edge j, lanes 32..63 edge j+1.
__global__ void aggregate_kernel(const __half* __restrict__ feat, const int* __restrict__ esrc,
                                 const int* __restrict__ offs, const int* __restrict__ cnt,
                                 __half* __restrict__ agg, int n) {
    int wid = (blockIdx.x * blockDim.x + threadIdx.x) >> 6;
    int lane = threadIdx.x & 63;
    if (wid >= n) return;
    int beg = offs[wid];
    int deg = cnt[wid];
    int half_id = lane >> 5;
    int colbase = (lane & 31) * 4;
    float a0 = 0.f, a1 = 0.f, a2 = 0.f, a3 = 0.f;

    for (int base = 0; base < deg; base += 64) {
        int m = min(64, deg - base);
        int idx = (lane < m) ? esrc[beg + base + lane] : 0;
#pragma unroll 4
        for (int j = 0; j < m; j += 2) {
            int jj = j + half_id;
            bool valid = jj < m;
            int s = __shfl(idx, valid ? jj : (m - 1));
            uint2 raw = *(const uint2*)(feat + (size_t)s * DFEAT + colbase);
            __half2 h01 = *(__half2*)&raw.x;
            __half2 h23 = *(__half2*)&raw.y;
            float2 f01 = __half22float2(h01);
            float2 f23 = __half22float2(h23);
            float w = valid ? 1.0f : 0.0f;
            a0 = fmaf(w, f01.x, a0);
            a1 = fmaf(w, f01.y, a1);
            a2 = fmaf(w, f23.x, a2);
            a3 = fmaf(w, f23.y, a3);
        }
    }
    a0 += __shfl_xor(a0, 32);
    a1 += __shfl_xor(a1, 32);
    a2 += __shfl_xor(a2, 32);
    a3 += __shfl_xor(a3, 32);

    if (lane < 32) {
        float scale = 1.0f / fmaxf((float)deg, 1.0f);
        __half2 h01 = __floats2half2_rn(a0 * scale, a1 * scale);
        __half2 h23 = __floats2half2_rn(a2 * scale, a3 * scale);
        uint2 o;
        o.x = *(unsigned int*)&h01;
        o.y = *(unsigned int*)&h23;
        *(uint2*)(agg + (size_t)wid * DFEAT + colbase) = o;
    }
}

// MFMA dual-GEMM: out[i][j] = sum_k A1[i][k]*Bl[j][k] + sum_k A2[i][k]*Br[j][k] + b[j]
// All inputs fp16, fp32 accumulate. No LDS, no barriers.
// Block: 256 threads (4 waves), M_block=128 (wave: 32 rows), N=128 full.
// NORM_RELU: L2-normalize + ReLU, write fp16 to out16 (may alias A1 rows: safe,
// each block writes only rows it alone reads). Else write fp32 to out32.
template <bool NORM_RELU>
__global__ __launch_bounds__(256) void gemm_mfma_kernel(
    const __half* __restrict__ A1_, const __half* __restrict__ A2_,
    const __half* __restrict__ Bl_, const __half* __restrict__ Br_,
    const float* __restrict__ bias, float* __restrict__ out32,
    __half* __restrict__ out16, int n) {
    const _Float16* A1 = (const _Float16*)A1_;
    const _Float16* A2 = (const _Float16*)A2_;
    const _Float16* Bl = (const _Float16*)Bl_;
    const _Float16* Br = (const _Float16*)Br_;

    const int lane = threadIdx.x & 63;
    const int w = threadIdx.x >> 6;       // wave 0..3
    const int quad = lane >> 4;           // 0..3
    const int l15 = lane & 15;
    const int i0 = blockIdx.x * 128 + w * 32;  // wave's first row

    floatx4 acc[2][8];
#pragma unroll
    for (int mt = 0; mt < 2; mt++)
#pragma unroll
        for (int nt = 0; nt < 8; nt++)
            acc[mt][nt] = (floatx4){0.f, 0.f, 0.f, 0.f};

    int r0 = i0 + l15;      if (r0 >= n) r0 = n - 1;
    int r1 = i0 + 16 + l15; if (r1 >= n) r1 = n - 1;
    const int kq = quad * 8;

#pragma unroll
    for (int half = 0; half < 2; half++) {
        const _Float16* A = half ? A2 : A1;
        const _Float16* B = half ? Br : Bl;
#pragma unroll
        for (int kc = 0; kc < DFEAT; kc += 32) {
            half8 a0 = *(const half8*)(A + (size_t)r0 * DFEAT + kc + kq);
            half8 a1 = *(const half8*)(A + (size_t)r1 * DFEAT + kc + kq);
#pragma unroll
            for (int nt = 0; nt < 8; nt++) {
                half8 b = *(const half8*)(B + (nt * 16 + l15) * DFEAT + kc + kq);
                acc[0][nt] = __builtin_amdgcn_mfma_f32_16x16x32_f16(a0, b, acc[0][nt], 0, 0, 0);
                acc[1][nt] = __builtin_amdgcn_mfma_f32_16x16x32_f16(a1, b, acc[1][nt], 0, 0, 0);
            }
        }
    }

    // bias per col group (col = nt*16 + l15)
    float bv[8];
#pragma unroll
    for (int nt = 0; nt < 8; nt++) bv[nt] = bias[nt * 16 + l15];

#pragma unroll
    for (int mt = 0; mt < 2; mt++) {
        float v[8][4];
#pragma unroll
        for (int nt = 0; nt < 8; nt++)
#pragma unroll
            for (int r = 0; r < 4; r++)
                v[nt][r] = acc[mt][nt][r] + bv[nt];

        if (NORM_RELU) {
#pragma unroll
            for (int r = 0; r < 4; r++) {
                float ss = 0.f;
#pragma unroll
                for (int nt = 0; nt < 8; nt++) ss = fmaf(v[nt][r], v[nt][r], ss);
                ss += __shfl_xor(ss, 1);
                ss += __shfl_xor(ss, 2);
                ss += __shfl_xor(ss, 4);
                ss += __shfl_xor(ss, 8);
                float inv = 1.0f / fmaxf(sqrtf(ss), 1e-12f);
#pragma unroll
                for (int nt = 0; nt < 8; nt++) v[nt][r] = fmaxf(v[nt][r] * inv, 0.0f);
            }
        }

#pragma unroll
        for (int r = 0; r < 4; r++) {
            int row = i0 + mt * 16 + quad * 4 + r;
            if (row < n) {
                if (NORM_RELU) {
                    __half* op = (__half*)out16 + (size_t)row * DFEAT + l15;
#pragma unroll
                    for (int nt = 0; nt < 8; nt++) op[nt * 16] = __float2half(v[nt][r]);
                } else {
                    float* op = out32 + (size_t)row * DFEAT + l15;
#pragma unroll
                    for (int nt = 0; nt < 8; nt++) op[nt * 16] = v[nt][r];
                }
            }
        }
    }
}

extern "C" void kernel_launch(void* const* d_in, const int* in_sizes, int n_in,
                              void* d_out, int out_size, void* d_ws, size_t ws_size,
                              hipStream_t stream) {
    const float* x = (const float*)d_in[0];
    const int* edge_index = (const int*)d_in[1];
    const float* W1l = (const float*)d_in[2];
    const float* b1 = (const float*)d_in[3];
    const float* W1r = (const float*)d_in[4];
    const float* W2l = (const float*)d_in[5];
    const float* b2 = (const float*)d_in[6];
    const float* W2r = (const float*)d_in[7];
    float* out = (float*)d_out;

    const int E = in_sizes[1] / 2;
    const int n = in_sizes[0] / DFEAT;  // 100000

    int* ws = (int*)d_ws;
    int* cnt = ws + WS_CNT;
    int* cursor = ws + WS_CURSOR;
    int* offs = ws + WS_OFFS;
    int* partial = ws + WS_PARTIAL;
    int* esrc = ws + WS_ESRC;
    __half* aggh = (__half*)(ws + WS_AGGH);
    __half* casth = (__half*)(ws + WS_CASTH);
    __half* wh = (__half*)(ws + WS_CURSOR);  // weights fp16, reuses cursor after scatter

    const int* src = edge_index;
    const int* dst = edge_index + E;

    hipMemsetAsync(cnt, 0, (size_t)2 * N_NODES * sizeof(int), stream);

    const int eb = (E + 255) / 256;
    hist_kernel<<<eb, 256, 0, stream>>>(dst, cnt, E);
    scan1_kernel<<<SCAN_BLOCKS, 256, 0, stream>>>(cnt, offs, partial, n);
    scan2_kernel<<<1, 512, 0, stream>>>(partial, SCAN_BLOCKS);
    scan3_kernel<<<SCAN_BLOCKS, 256, 0, stream>>>(offs, partial, n);
    scatter_kernel<<<eb, 256, 0, stream>>>(src, dst, offs, cursor, esrc, E);

    const int total4 = n * DFEAT / 4;
    cast_kernel<<<(total4 + 255) / 256, 256, 0, stream>>>(x, casth, total4);
    // after scatter, cursor region is free -> weights fp16
    cast_w_kernel<<<64, 256, 0, stream>>>(W1l, W1r, W2l, W2r, wh);

    const int aggb = (n * 64 + 255) / 256;  // one wave per node
    const int gemmb = (n + 127) / 128;

    // layer 1: agg(x_h) -> aggh; h = relu(normalize(aggh@W1l^T + b1 + x_h@W1r^T))
    // h written fp16 IN PLACE into aggh (block-local rows only)
    aggregate_kernel<<<aggb, 256, 0, stream>>>(casth, esrc, offs, cnt, aggh, n);
    gemm_mfma_kernel<true><<<gemmb, 256, 0, stream>>>(
        aggh, casth, wh, wh + 16384, b1, nullptr, aggh, n);

    // layer 2: agg(h) -> casth; out = casth@W2l^T + b2 + h@W2r^T (fp32 to d_out)
    aggregate_kernel<<<aggb, 256, 0, stream>>>(aggh, esrc, offs, cnt, casth, n);
    gemm_mfma_kernel<false><<<gemmb, 256, 0, stream>>>(
        casth, aggh, wh + 32768, wh + 49152, b2, out, nullptr, n);
}

// Round 4
// 471.502 us; speedup vs baseline: 1.4170x; 1.0972x over previous
//
#include <hip/hip_runtime.h>
#include <hip/hip_bf16.h>
#include <hip/hip_fp16.h>

#define N_NODES 100000
#define DFEAT 128
#define SCAN_BLOCKS 391   // ceil(100000/256)
#define SLAB 4096         // edges per partition block
#define BSHIFT 9          // 512 nodes per bucket
#define NBUCK 196         // ceil(100000/512)

// ---------------- ws layout (4-byte units) ----------------
// cnt    [0      , 100000)
// gh     [100000 , 176636)   bucket-major (bucket,block) histogram -> scanned bases
//   (region later reused: wh fp16 weights at [100000,132768), partialB at [180000,180512))
// offs   [200000 , 300096)
// partialA[300096, 300608)
// esrc   [300608 , 1900608)
// aggh   [1900608, 8300608)   first: int2 pairs buffer (3.2M ints); then fp16 agg1 / h
// casth  [8300608, 14700608)  fp16 x_h, then agg2
#define WS_CNT      0
#define WS_GH       100000
#define WS_PARTB    180000
#define WS_OFFS     200000
#define WS_PARTA    300096
#define WS_ESRC     300608
#define WS_AGGH     1900608
#define WS_CASTH    8300608

typedef _Float16 half8 __attribute__((ext_vector_type(8)));
typedef float floatx4 __attribute__((ext_vector_type(4)));

// ---------- generic exclusive-scan trio (in may alias out) ----------
__global__ void scan1_kernel(const int* in, int* out, int* partial, int n) {
    __shared__ int s[256];
    int i = blockIdx.x * 256 + threadIdx.x;
    int v = (i < n) ? in[i] : 0;
    s[threadIdx.x] = v;
    __syncthreads();
    for (int d = 1; d < 256; d <<= 1) {
        int t = (threadIdx.x >= d) ? s[threadIdx.x - d] : 0;
        __syncthreads();
        s[threadIdx.x] += t;
        __syncthreads();
    }
    int incl = s[threadIdx.x];
    if (i < n) out[i] = incl - v;               // exclusive
    if (threadIdx.x == 255) partial[blockIdx.x] = incl;
}

__global__ void scan2_kernel(int* partial, int nb) {
    __shared__ int s[512];
    int t = threadIdx.x;
    int v = (t < nb) ? partial[t] : 0;
    s[t] = v;
    __syncthreads();
    for (int d = 1; d < 512; d <<= 1) {
        int u = (t >= d) ? s[t - d] : 0;
        __syncthreads();
        s[t] += u;
        __syncthreads();
    }
    if (t < nb) partial[t] = s[t] - v;          // exclusive
}

__global__ void scan3_kernel(int* out, const int* partial, int n) {
    int i = blockIdx.x * 256 + threadIdx.x;
    if (i < n) out[i] += partial[blockIdx.x];
}

// ---------- phase 1: per-node hist + per-(bucket,block) hist ----------
__global__ __launch_bounds__(256) void phase1_kernel(const int* __restrict__ dst,
                                                     int* __restrict__ cnt,
                                                     int* __restrict__ gh,
                                                     int E, int bpart) {
    __shared__ int lh[NBUCK];
    int b = blockIdx.x;
    for (int i = threadIdx.x; i < NBUCK; i += 256) lh[i] = 0;
    __syncthreads();
    int s0 = b * SLAB, s1 = min(E, s0 + SLAB);
    for (int i = s0 + threadIdx.x; i < s1; i += 256) {
        int d = dst[i];
        atomicAdd(&cnt[d], 1);
        atomicAdd(&lh[d >> BSHIFT], 1);
    }
    __syncthreads();
    for (int i = threadIdx.x; i < NBUCK; i += 256) gh[i * bpart + b] = lh[i];
}

// ---------- phase 2: LDS counting-sort slab by bucket, copy runs out ----------
__global__ __launch_bounds__(256) void phase2_kernel(const int* __restrict__ src,
                                                     const int* __restrict__ dst,
                                                     const int* __restrict__ gbase,
                                                     int2* __restrict__ pairs,
                                                     int E, int bpart) {
    __shared__ int lbase[NBUCK];
    __shared__ int lcur[NBUCK];
    __shared__ int lgb[NBUCK];
    __shared__ int sc[256];
    __shared__ int2 lp[SLAB];   // 32 KB
    int b = blockIdx.x;
    int t = threadIdx.x;
    for (int i = t; i < NBUCK; i += 256) lbase[i] = 0;
    __syncthreads();
    int s0 = b * SLAB, s1 = min(E, s0 + SLAB);
    for (int i = s0 + t; i < s1; i += 256)
        atomicAdd(&lbase[dst[i] >> BSHIFT], 1);
    __syncthreads();
    // exclusive scan of lbase (NBUCK<=256) via Hillis-Steele
    int v = (t < NBUCK) ? lbase[t] : 0;
    sc[t] = v;
    __syncthreads();
    for (int d = 1; d < 256; d <<= 1) {
        int u = (t >= d) ? sc[t - d] : 0;
        __syncthreads();
        sc[t] += u;
        __syncthreads();
    }
    if (t < NBUCK) {
        int excl = sc[t] - v;
        lbase[t] = excl;
        lcur[t] = excl;
        lgb[t] = gbase[t * bpart + b];
    }
    __syncthreads();
    // place edges into LDS in bucket order
    for (int i = s0 + t; i < s1; i += 256) {
        int d = dst[i];
        int s = src[i];
        int bk = d >> BSHIFT;
        int pos = atomicAdd(&lcur[bk], 1);
        lp[pos] = make_int2(s, d);
    }
    __syncthreads();
    // copy runs to exclusive global regions (coalesced within runs)
    int m = s1 - s0;
    for (int i = t; i < m; i += 256) {
        int2 p = lp[i];
        int bk = p.y >> BSHIFT;
        pairs[lgb[bk] + (i - lbase[bk])] = p;
    }
}

// ---------- phase 3: finalize CSR within one bucket (LDS cursors) ----------
__global__ __launch_bounds__(256) void phase3_kernel(const int2* __restrict__ pairs,
                                                     const int* __restrict__ gbase,
                                                     const int* __restrict__ offs,
                                                     int* __restrict__ esrc,
                                                     int E, int bpart, int n) {
    __shared__ int lcur[512];
    __shared__ int loffs[512];
    int g = blockIdx.x;
    int node0 = g << BSHIFT;
    for (int i = threadIdx.x; i < 512; i += 256) {
        lcur[i] = 0;
        int nd = node0 + i;
        loffs[i] = (nd < n) ? offs[nd] : 0;
    }
    __syncthreads();
    int S = gbase[g * bpart];
    int Eg = (g == (int)gridDim.x - 1) ? E : gbase[(g + 1) * bpart];
    for (int i = S + threadIdx.x; i < Eg; i += 256) {
        int2 p = pairs[i];
        int local = p.y - node0;
        int pos = atomicAdd(&lcur[local], 1);
        esrc[loffs[local] + pos] = p.x;
    }
}

// fp32 -> fp16 cast, 4 elements/thread
__global__ void cast_kernel(const float* __restrict__ x, __half* __restrict__ xh, int total4) {
    int i = blockIdx.x * blockDim.x + threadIdx.x;
    if (i >= total4) return;
    float4 v = ((const float4*)x)[i];
    __half2 h01 = __floats2half2_rn(v.x, v.y);
    __half2 h23 = __floats2half2_rn(v.z, v.w);
    uint2 o;
    o.x = *(unsigned int*)&h01;
    o.y = *(unsigned int*)&h23;
    ((uint2*)xh)[i] = o;
}

// cast 4 weight matrices (128x128 fp32) to fp16, packed [W1l|W1r|W2l|W2r]
__global__ void cast_w_kernel(const float* __restrict__ W1l, const float* __restrict__ W1r,
                              const float* __restrict__ W2l, const float* __restrict__ W2r,
                              __half* __restrict__ wh) {
    int i = blockIdx.x * blockDim.x + threadIdx.x;  // 0..16383 (x4 elems)
    if (i >= 16384) return;
    const float* srcs[4] = {W1l, W1r, W2l, W2r};
    int m = i >> 12;
    int j = (i & 4095) * 4;
    float4 v = *(const float4*)(srcs[m] + j);
    __half2 h01 = __floats2half2_rn(v.x, v.y);
    __half2 h23 = __floats2half2_rn(v.z, v.w);
    uint2 o;
    o.x = *(unsigned int*)&h01;
    o.y = *(unsigned int*)&h23;
    *(uint2*)(wh + m * 16384 + j) = o;
}

// one wave per node. Pair mode: lanes 0..31 handle edge j, lanes 32..63 edge j+1.
__global__ void aggregate_kernel(const __half* __restrict__ feat, const int* __restrict__ esrc,
                                 const int* __restrict__ offs, const int* __restrict__ cnt,
                                 __half* __restrict__ agg, int n) {
    int wid = (blockIdx.x * blockDim.x + threadIdx.x) >> 6;
    int lane = threadIdx.x & 63;
    if (wid >= n) return;
    int beg = offs[wid];
    int deg = cnt[wid];
    int half_id = lane >> 5;
    int colbase = (lane & 31) * 4;
    float a0 = 0.f, a1 = 0.f, a2 = 0.f, a3 = 0.f;

    for (int base = 0; base < deg; base += 64) {
        int m = min(64, deg - base);
        int idx = (lane < m) ? esrc[beg + base + lane] : 0;
#pragma unroll 4
        for (int j = 0; j < m; j += 2) {
            int jj = j + half_id;
            bool valid = jj < m;
            int s = __shfl(idx, valid ? jj : (m - 1));
            uint2 raw = *(const uint2*)(feat + (size_t)s * DFEAT + colbase);
            __half2 h01 = *(__half2*)&raw.x;
            __half2 h23 = *(__half2*)&raw.y;
            float2 f01 = __half22float2(h01);
            float2 f23 = __half22float2(h23);
            float w = valid ? 1.0f : 0.0f;
            a0 = fmaf(w, f01.x, a0);
            a1 = fmaf(w, f01.y, a1);
            a2 = fmaf(w, f23.x, a2);
            a3 = fmaf(w, f23.y, a3);
        }
    }
    a0 += __shfl_xor(a0, 32);
    a1 += __shfl_xor(a1, 32);
    a2 += __shfl_xor(a2, 32);
    a3 += __shfl_xor(a3, 32);

    if (lane < 32) {
        float scale = 1.0f / fmaxf((float)deg, 1.0f);
        __half2 h01 = __floats2half2_rn(a0 * scale, a1 * scale);
        __half2 h23 = __floats2half2_rn(a2 * scale, a3 * scale);
        uint2 o;
        o.x = *(unsigned int*)&h01;
        o.y = *(unsigned int*)&h23;
        *(uint2*)(agg + (size_t)wid * DFEAT + colbase) = o;
    }
}

// MFMA dual-GEMM: out[i][j] = sum_k A1[i][k]*Bl[j][k] + sum_k A2[i][k]*Br[j][k] + b[j]
// All inputs fp16, fp32 accumulate. No LDS, no barriers.
template <bool NORM_RELU>
__global__ __launch_bounds__(256) void gemm_mfma_kernel(
    const __half* __restrict__ A1_, const __half* __restrict__ A2_,
    const __half* __restrict__ Bl_, const __half* __restrict__ Br_,
    const float* __restrict__ bias, float* __restrict__ out32,
    __half* __restrict__ out16, int n) {
    const _Float16* A1 = (const _Float16*)A1_;
    const _Float16* A2 = (const _Float16*)A2_;
    const _Float16* Bl = (const _Float16*)Bl_;
    const _Float16* Br = (const _Float16*)Br_;

    const int lane = threadIdx.x & 63;
    const int w = threadIdx.x >> 6;       // wave 0..3
    const int quad = lane >> 4;           // 0..3
    const int l15 = lane & 15;
    const int i0 = blockIdx.x * 128 + w * 32;

    floatx4 acc[2][8];
#pragma unroll
    for (int mt = 0; mt < 2; mt++)
#pragma unroll
        for (int nt = 0; nt < 8; nt++)
            acc[mt][nt] = (floatx4){0.f, 0.f, 0.f, 0.f};

    int r0 = i0 + l15;      if (r0 >= n) r0 = n - 1;
    int r1 = i0 + 16 + l15; if (r1 >= n) r1 = n - 1;
    const int kq = quad * 8;

#pragma unroll
    for (int half = 0; half < 2; half++) {
        const _Float16* A = half ? A2 : A1;
        const _Float16* B = half ? Br : Bl;
#pragma unroll
        for (int kc = 0; kc < DFEAT; kc += 32) {
            half8 a0 = *(const half8*)(A + (size_t)r0 * DFEAT + kc + kq);
            half8 a1 = *(const half8*)(A + (size_t)r1 * DFEAT + kc + kq);
#pragma unroll
            for (int nt = 0; nt < 8; nt++) {
                half8 b = *(const half8*)(B + (nt * 16 + l15) * DFEAT + kc + kq);
                acc[0][nt] = __builtin_amdgcn_mfma_f32_16x16x32_f16(a0, b, acc[0][nt], 0, 0, 0);
                acc[1][nt] = __builtin_amdgcn_mfma_f32_16x16x32_f16(a1, b, acc[1][nt], 0, 0, 0);
            }
        }
    }

    float bv[8];
#pragma unroll
    for (int nt = 0; nt < 8; nt++) bv[nt] = bias[nt * 16 + l15];

#pragma unroll
    for (int mt = 0; mt < 2; mt++) {
        float v[8][4];
#pragma unroll
        for (int nt = 0; nt < 8; nt++)
#pragma unroll
            for (int r = 0; r < 4; r++)
                v[nt][r] = acc[mt][nt][r] + bv[nt];

        if (NORM_RELU) {
#pragma unroll
            for (int r = 0; r < 4; r++) {
                float ss = 0.f;
#pragma unroll
                for (int nt = 0; nt < 8; nt++) ss = fmaf(v[nt][r], v[nt][r], ss);
                ss += __shfl_xor(ss, 1);
                ss += __shfl_xor(ss, 2);
                ss += __shfl_xor(ss, 4);
                ss += __shfl_xor(ss, 8);
                float inv = 1.0f / fmaxf(sqrtf(ss), 1e-12f);
#pragma unroll
                for (int nt = 0; nt < 8; nt++) v[nt][r] = fmaxf(v[nt][r] * inv, 0.0f);
            }
        }

#pragma unroll
        for (int r = 0; r < 4; r++) {
            int row = i0 + mt * 16 + quad * 4 + r;
            if (row < n) {
                if (NORM_RELU) {
                    __half* op = (__half*)out16 + (size_t)row * DFEAT + l15;
#pragma unroll
                    for (int nt = 0; nt < 8; nt++) op[nt * 16] = __float2half(v[nt][r]);
                } else {
                    float* op = out32 + (size_t)row * DFEAT + l15;
#pragma unroll
                    for (int nt = 0; nt < 8; nt++) op[nt * 16] = v[nt][r];
                }
            }
        }
    }
}

extern "C" void kernel_launch(void* const* d_in, const int* in_sizes, int n_in,
                              void* d_out, int out_size, void* d_ws, size_t ws_size,
                              hipStream_t stream) {
    const float* x = (const float*)d_in[0];
    const int* edge_index = (const int*)d_in[1];
    const float* W1l = (const float*)d_in[2];
    const float* b1 = (const float*)d_in[3];
    const float* W1r = (const float*)d_in[4];
    const float* W2l = (const float*)d_in[5];
    const float* b2 = (const float*)d_in[6];
    const float* W2r = (const float*)d_in[7];
    float* out = (float*)d_out;

    const int E = in_sizes[1] / 2;
    const int n = in_sizes[0] / DFEAT;  // 100000

    int* ws = (int*)d_ws;
    int* cnt = ws + WS_CNT;
    int* gh = ws + WS_GH;
    int* partialB = ws + WS_PARTB;
    int* offs = ws + WS_OFFS;
    int* partialA = ws + WS_PARTA;
    int* esrc = ws + WS_ESRC;
    int2* pairs = (int2*)(ws + WS_AGGH);     // dead after phase3; aggh reuses
    __half* aggh = (__half*)(ws + WS_AGGH);
    __half* casth = (__half*)(ws + WS_CASTH);
    __half* wh = (__half*)(ws + WS_GH);      // weights fp16; gh dead after phase3

    const int* src = edge_index;
    const int* dst = edge_index + E;

    const int bpart = (E + SLAB - 1) / SLAB;        // 391
    const int m = NBUCK * bpart;                    // 76636
    const int blocksB = (m + 255) / 256;            // 300

    hipMemsetAsync(cnt, 0, (size_t)N_NODES * sizeof(int), stream);

    phase1_kernel<<<bpart, 256, 0, stream>>>(dst, cnt, gh, E, bpart);
    // node offsets
    scan1_kernel<<<SCAN_BLOCKS, 256, 0, stream>>>(cnt, offs, partialA, n);
    scan2_kernel<<<1, 512, 0, stream>>>(partialA, SCAN_BLOCKS);
    scan3_kernel<<<SCAN_BLOCKS, 256, 0, stream>>>(offs, partialA, n);
    // (bucket,block) bases, in place
    scan1_kernel<<<blocksB, 256, 0, stream>>>(gh, gh, partialB, m);
    scan2_kernel<<<1, 512, 0, stream>>>(partialB, blocksB);
    scan3_kernel<<<blocksB, 256, 0, stream>>>(gh, partialB, m);

    phase2_kernel<<<bpart, 256, 0, stream>>>(src, dst, gh, pairs, E, bpart);
    phase3_kernel<<<NBUCK, 256, 0, stream>>>(pairs, gh, offs, esrc, E, bpart, n);

    const int total4 = n * DFEAT / 4;
    cast_kernel<<<(total4 + 255) / 256, 256, 0, stream>>>(x, casth, total4);
    cast_w_kernel<<<64, 256, 0, stream>>>(W1l, W1r, W2l, W2r, wh);  // overwrites gh (dead)

    const int aggb = (n * 64 + 255) / 256;
    const int gemmb = (n + 127) / 128;

    // layer 1
    aggregate_kernel<<<aggb, 256, 0, stream>>>(casth, esrc, offs, cnt, aggh, n);
    gemm_mfma_kernel<true><<<gemmb, 256, 0, stream>>>(
        aggh, casth, wh, wh + 16384, b1, nullptr, aggh, n);

    // layer 2
    aggregate_kernel<<<aggb, 256, 0, stream>>>(aggh, esrc, offs, cnt, casth, n);
    gemm_mfma_kernel<false><<<gemmb, 256, 0, stream>>>(
        casth, aggh, wh + 32768, wh + 49152, b2, out, nullptr, n);
}

// Round 5
// 460.366 us; speedup vs baseline: 1.4513x; 1.0242x over previous
//
#include <hip/hip_runtime.h>
#include <hip/hip_bf16.h>
#include <hip/hip_fp16.h>

#define N_NODES 100000
#define DFEAT 128
#define SCAN_BLOCKS 391   // ceil(100000/256)
#define SLAB 4096         // edges per partition block
#define BSHIFT 9          // 512 nodes per bucket
#define NBUCK 196         // ceil(100000/512)

// ---------------- ws layout (4-byte units) ----------------
// cnt    [0      , 100000)
// gh     [100000 , 176636)   bucket-major (bucket,block) histogram -> scanned bases
// partialB[180000, 180512)
// offs   [200000 , 300096)
// partialA[300096, 300608)
// esrc   [300608 , 1900608)
// aggh   [1900608, 8300608)   first: int2 pairs buffer; then fp16 agg1 / h
// casth  [8300608, 14700608)  fp16 x_h, then agg2
#define WS_CNT      0
#define WS_GH       100000
#define WS_PARTB    180000
#define WS_OFFS     200000
#define WS_PARTA    300096
#define WS_ESRC     300608
#define WS_AGGH     1900608
#define WS_CASTH    8300608

typedef _Float16 half8 __attribute__((ext_vector_type(8)));
typedef _Float16 half2v __attribute__((ext_vector_type(2)));
typedef float floatx4 __attribute__((ext_vector_type(4)));

// ---------- fused prep: cast x->fp16 (blocks < castblocks) + phase1 hist ----------
__global__ __launch_bounds__(256) void prep_kernel(const float* __restrict__ x,
                                                   __half* __restrict__ xh, int total4,
                                                   const int* __restrict__ dst,
                                                   int* __restrict__ cnt,
                                                   int* __restrict__ gh,
                                                   int E, int bpart, int castblocks) {
    __shared__ int lh[NBUCK];
    int b = blockIdx.x;
    if (b < castblocks) {
        int i = b * 256 + threadIdx.x;
        if (i < total4) {
            float4 v = ((const float4*)x)[i];
            __half2 h01 = __floats2half2_rn(v.x, v.y);
            __half2 h23 = __floats2half2_rn(v.z, v.w);
            uint2 o;
            o.x = *(unsigned int*)&h01;
            o.y = *(unsigned int*)&h23;
            ((uint2*)xh)[i] = o;
        }
        return;
    }
    int bb = b - castblocks;
    for (int i = threadIdx.x; i < NBUCK; i += 256) lh[i] = 0;
    __syncthreads();
    int s0 = bb * SLAB, s1 = min(E, s0 + SLAB);
    for (int i = s0 + threadIdx.x; i < s1; i += 256) {
        int d = dst[i];
        atomicAdd(&cnt[d], 1);
        atomicAdd(&lh[d >> BSHIFT], 1);
    }
    __syncthreads();
    for (int i = threadIdx.x; i < NBUCK; i += 256) gh[i * bpart + bb] = lh[i];
}

// ---------- combined scans (offs over cnt; gh in-place) ----------
__global__ void scanA_kernel(const int* __restrict__ cnt, int* __restrict__ offs,
                             int* __restrict__ partialA, int* __restrict__ gh,
                             int* __restrict__ partialB, int n, int m) {
    __shared__ int s[256];
    int b = blockIdx.x;
    const int* in;
    int *out, *partial, nn, bb;
    if (b < SCAN_BLOCKS) { in = cnt; out = offs; partial = partialA; nn = n; bb = b; }
    else { in = gh; out = gh; partial = partialB; nn = m; bb = b - SCAN_BLOCKS; }
    int i = bb * 256 + threadIdx.x;
    int v = (i < nn) ? in[i] : 0;
    s[threadIdx.x] = v;
    __syncthreads();
    for (int d = 1; d < 256; d <<= 1) {
        int t = (threadIdx.x >= d) ? s[threadIdx.x - d] : 0;
        __syncthreads();
        s[threadIdx.x] += t;
        __syncthreads();
    }
    int incl = s[threadIdx.x];
    if (i < nn) out[i] = incl - v;
    if (threadIdx.x == 255) partial[bb] = incl;
}

__global__ void scanB_kernel(int* __restrict__ partialA, int nA,
                             int* __restrict__ partialB, int nB) {
    __shared__ int s[512];
    int* p = blockIdx.x ? partialB : partialA;
    int nb = blockIdx.x ? nB : nA;
    int t = threadIdx.x;
    int v = (t < nb) ? p[t] : 0;
    s[t] = v;
    __syncthreads();
    for (int d = 1; d < 512; d <<= 1) {
        int u = (t >= d) ? s[t - d] : 0;
        __syncthreads();
        s[t] += u;
        __syncthreads();
    }
    if (t < nb) p[t] = s[t] - v;
}

__global__ void scanC_kernel(int* __restrict__ offs, const int* __restrict__ partialA,
                             int* __restrict__ gh, const int* __restrict__ partialB,
                             int n, int m) {
    int b = blockIdx.x;
    if (b < SCAN_BLOCKS) {
        int i = b * 256 + threadIdx.x;
        if (i < n) offs[i] += partialA[b];
    } else {
        int bb = b - SCAN_BLOCKS;
        int i = bb * 256 + threadIdx.x;
        if (i < m) gh[i] += partialB[bb];
    }
}

// ---------- phase 2: LDS counting-sort slab by bucket, copy runs out ----------
__global__ __launch_bounds__(256) void phase2_kernel(const int* __restrict__ src,
                                                     const int* __restrict__ dst,
                                                     const int* __restrict__ gbase,
                                                     int2* __restrict__ pairs,
                                                     int E, int bpart) {
    __shared__ int lbase[NBUCK];
    __shared__ int lcur[NBUCK];
    __shared__ int lgb[NBUCK];
    __shared__ int sc[256];
    __shared__ int2 lp[SLAB];   // 32 KB
    int b = blockIdx.x;
    int t = threadIdx.x;
    for (int i = t; i < NBUCK; i += 256) lbase[i] = 0;
    __syncthreads();
    int s0 = b * SLAB, s1 = min(E, s0 + SLAB);
    for (int i = s0 + t; i < s1; i += 256)
        atomicAdd(&lbase[dst[i] >> BSHIFT], 1);
    __syncthreads();
    int v = (t < NBUCK) ? lbase[t] : 0;
    sc[t] = v;
    __syncthreads();
    for (int d = 1; d < 256; d <<= 1) {
        int u = (t >= d) ? sc[t - d] : 0;
        __syncthreads();
        sc[t] += u;
        __syncthreads();
    }
    if (t < NBUCK) {
        int excl = sc[t] - v;
        lbase[t] = excl;
        lcur[t] = excl;
        lgb[t] = gbase[t * bpart + b];
    }
    __syncthreads();
    for (int i = s0 + t; i < s1; i += 256) {
        int d = dst[i];
        int s = src[i];
        int bk = d >> BSHIFT;
        int pos = atomicAdd(&lcur[bk], 1);
        lp[pos] = make_int2(s, d);
    }
    __syncthreads();
    int m = s1 - s0;
    for (int i = t; i < m; i += 256) {
        int2 p = lp[i];
        int bk = p.y >> BSHIFT;
        pairs[lgb[bk] + (i - lbase[bk])] = p;
    }
}

// ---------- phase 3: finalize CSR within one bucket (LDS cursors) ----------
__global__ __launch_bounds__(256) void phase3_kernel(const int2* __restrict__ pairs,
                                                     const int* __restrict__ gbase,
                                                     const int* __restrict__ offs,
                                                     int* __restrict__ esrc,
                                                     int E, int bpart, int n) {
    __shared__ int lcur[512];
    __shared__ int loffs[512];
    int g = blockIdx.x;
    int node0 = g << BSHIFT;
    for (int i = threadIdx.x; i < 512; i += 256) {
        lcur[i] = 0;
        int nd = node0 + i;
        loffs[i] = (nd < n) ? offs[nd] : 0;
    }
    __syncthreads();
    int S = gbase[g * bpart];
    int Eg = (g == (int)gridDim.x - 1) ? E : gbase[(g + 1) * bpart];
    for (int i = S + threadIdx.x; i < Eg; i += 256) {
        int2 p = pairs[i];
        int local = p.y - node0;
        int pos = atomicAdd(&lcur[local], 1);
        esrc[loffs[local] + pos] = p.x;
    }
}

// ---------- aggregate: one wave per node, packed-fp16 accumulate ----------
__global__ void aggregate_kernel(const __half* __restrict__ feat, const int* __restrict__ esrc,
                                 const int* __restrict__ offs, const int* __restrict__ cnt,
                                 __half* __restrict__ agg, int n) {
    int wid = (blockIdx.x * blockDim.x + threadIdx.x) >> 6;
    int lane = threadIdx.x & 63;
    if (wid >= n) return;
    int beg = offs[wid];
    int deg = cnt[wid];
    int half_id = lane >> 5;
    int colbase = (lane & 31) * 4;
    half2v s01 = (half2v)(_Float16)0;
    half2v s23 = (half2v)(_Float16)0;

    for (int base = 0; base < deg; base += 64) {
        int m = min(64, deg - base);
        int idx = (lane < m) ? esrc[beg + base + lane] : 0;
#pragma unroll 8
        for (int j = 0; j < m; j += 2) {
            int jj = j + half_id;
            bool valid = jj < m;
            int s = __shfl(idx, valid ? jj : (m - 1));
            uint2 raw = *(const uint2*)(feat + (size_t)s * DFEAT + colbase);
            if (!valid) { raw.x = 0u; raw.y = 0u; }
            s01 += *(half2v*)&raw.x;
            s23 += *(half2v*)&raw.y;
        }
    }
    float a0 = (float)s01.x, a1 = (float)s01.y;
    float a2 = (float)s23.x, a3 = (float)s23.y;
    a0 += __shfl_xor(a0, 32);
    a1 += __shfl_xor(a1, 32);
    a2 += __shfl_xor(a2, 32);
    a3 += __shfl_xor(a3, 32);

    if (lane < 32) {
        float scale = 1.0f / fmaxf((float)deg, 1.0f);
        __half2 h01 = __floats2half2_rn(a0 * scale, a1 * scale);
        __half2 h23 = __floats2half2_rn(a2 * scale, a3 * scale);
        uint2 o;
        o.x = *(unsigned int*)&h01;
        o.y = *(unsigned int*)&h23;
        *(uint2*)(agg + (size_t)wid * DFEAT + colbase) = o;
    }
}

// ---------- MFMA dual-GEMM, LDS-staged weights, D[feat][node] orientation ----------
// out[i][j] = sum_k A1[i][k]*Wl[j][k] + sum_k A2[i][k]*Wr[j][k] + b[j]
// a_frag = weight rows (m=feat), b_frag = node rows (n=node) =>
// D: row(quad*4+reg)=feat, col(lane&15)=node -> lane owns 4 contiguous feats of 1 node.
// Weights read fp32 from global, cast to fp16 while staging into LDS (stride 136).
template <bool NORM_RELU>
__global__ __launch_bounds__(256) void gemm_mfma_kernel(
    const __half* __restrict__ A1_, const __half* __restrict__ A2_,
    const float* __restrict__ Wl, const float* __restrict__ Wr,
    const float* __restrict__ bias, float* __restrict__ out32,
    __half* __restrict__ out16, int n) {
    __shared__ __align__(16) _Float16 lw[128 * 136];   // 34.8 KB

    const _Float16* A1 = (const _Float16*)A1_;
    const _Float16* A2 = (const _Float16*)A2_;

    const int lane = threadIdx.x & 63;
    const int w = threadIdx.x >> 6;       // wave 0..3
    const int quad = lane >> 4;           // 0..3
    const int l15 = lane & 15;
    const int i0 = blockIdx.x * 128 + w * 32;   // wave's first node row

    floatx4 acc[2][8];
#pragma unroll
    for (int nt = 0; nt < 2; nt++)
#pragma unroll
        for (int ft = 0; ft < 8; ft++)
            acc[nt][ft] = (floatx4){0.f, 0.f, 0.f, 0.f};

    int r0 = i0 + l15;      if (r0 >= n) r0 = n - 1;
    int r1 = i0 + 16 + l15; if (r1 >= n) r1 = n - 1;
    const int kq = quad * 8;

    for (int half = 0; half < 2; half++) {
        const float* __restrict__ W = half ? Wr : Wl;
        const _Float16* __restrict__ A = half ? A2 : A1;
        if (half) __syncthreads();   // protect lw from waves still in previous K-loop
        // stage W fp32 -> fp16 LDS (row stride 136 halves = 272 B, 16B-aligned)
        {
            int t = threadIdx.x;
            int row = t >> 1;
            int cb = (t & 1) * 64;
            const float4* sp = (const float4*)(W + row * DFEAT + cb);
            unsigned int* dp = (unsigned int*)&lw[row * 136 + cb];
#pragma unroll
            for (int q = 0; q < 16; q++) {
                float4 v = sp[q];
                __half2 h01 = __floats2half2_rn(v.x, v.y);
                __half2 h23 = __floats2half2_rn(v.z, v.w);
                dp[q * 2] = *(unsigned int*)&h01;
                dp[q * 2 + 1] = *(unsigned int*)&h23;
            }
        }
        __syncthreads();
#pragma unroll
        for (int kc = 0; kc < DFEAT; kc += 32) {
            half8 b0 = *(const half8*)(A + (size_t)r0 * DFEAT + kc + kq);
            half8 b1 = *(const half8*)(A + (size_t)r1 * DFEAT + kc + kq);
#pragma unroll
            for (int ft = 0; ft < 8; ft++) {
                half8 a = *(const half8*)&lw[(ft * 16 + l15) * 136 + kc + kq];
                acc[0][ft] = __builtin_amdgcn_mfma_f32_16x16x32_f16(a, b0, acc[0][ft], 0, 0, 0);
                acc[1][ft] = __builtin_amdgcn_mfma_f32_16x16x32_f16(a, b1, acc[1][ft], 0, 0, 0);
            }
        }
    }

#pragma unroll
    for (int nt = 0; nt < 2; nt++) {
        int node = i0 + nt * 16 + l15;
        float v[8][4];
#pragma unroll
        for (int ft = 0; ft < 8; ft++) {
            const float4 bq = *(const float4*)(bias + ft * 16 + quad * 4);
            v[ft][0] = acc[nt][ft][0] + bq.x;
            v[ft][1] = acc[nt][ft][1] + bq.y;
            v[ft][2] = acc[nt][ft][2] + bq.z;
            v[ft][3] = acc[nt][ft][3] + bq.w;
        }
        if (NORM_RELU) {
            float ss = 0.f;
#pragma unroll
            for (int ft = 0; ft < 8; ft++)
#pragma unroll
                for (int r = 0; r < 4; r++) ss = fmaf(v[ft][r], v[ft][r], ss);
            ss += __shfl_xor(ss, 16);
            ss += __shfl_xor(ss, 32);
            float inv = 1.0f / fmaxf(sqrtf(ss), 1e-12f);
#pragma unroll
            for (int ft = 0; ft < 8; ft++)
#pragma unroll
                for (int r = 0; r < 4; r++) v[ft][r] = fmaxf(v[ft][r] * inv, 0.0f);
        }
        if (node < n) {
            if (NORM_RELU) {
                __half* op = (__half*)out16 + (size_t)node * DFEAT + quad * 4;
#pragma unroll
                for (int ft = 0; ft < 8; ft++) {
                    __half2 h01 = __floats2half2_rn(v[ft][0], v[ft][1]);
                    __half2 h23 = __floats2half2_rn(v[ft][2], v[ft][3]);
                    uint2 o;
                    o.x = *(unsigned int*)&h01;
                    o.y = *(unsigned int*)&h23;
                    *(uint2*)(op + ft * 16) = o;
                }
            } else {
                float* op = out32 + (size_t)node * DFEAT + quad * 4;
#pragma unroll
                for (int ft = 0; ft < 8; ft++)
                    *(float4*)(op + ft * 16) = make_float4(v[ft][0], v[ft][1], v[ft][2], v[ft][3]);
            }
        }
    }
}

extern "C" void kernel_launch(void* const* d_in, const int* in_sizes, int n_in,
                              void* d_out, int out_size, void* d_ws, size_t ws_size,
                              hipStream_t stream) {
    const float* x = (const float*)d_in[0];
    const int* edge_index = (const int*)d_in[1];
    const float* W1l = (const float*)d_in[2];
    const float* b1 = (const float*)d_in[3];
    const float* W1r = (const float*)d_in[4];
    const float* W2l = (const float*)d_in[5];
    const float* b2 = (const float*)d_in[6];
    const float* W2r = (const float*)d_in[7];
    float* out = (float*)d_out;

    const int E = in_sizes[1] / 2;
    const int n = in_sizes[0] / DFEAT;  // 100000

    int* ws = (int*)d_ws;
    int* cnt = ws + WS_CNT;
    int* gh = ws + WS_GH;
    int* partialB = ws + WS_PARTB;
    int* offs = ws + WS_OFFS;
    int* partialA = ws + WS_PARTA;
    int* esrc = ws + WS_ESRC;
    int2* pairs = (int2*)(ws + WS_AGGH);
    __half* aggh = (__half*)(ws + WS_AGGH);
    __half* casth = (__half*)(ws + WS_CASTH);

    const int* src = edge_index;
    const int* dst = edge_index + E;

    const int bpart = (E + SLAB - 1) / SLAB;        // 391
    const int m = NBUCK * bpart;                    // 76636
    const int blocksB = (m + 255) / 256;            // 300
    const int total4 = n * DFEAT / 4;
    const int castblocks = (total4 + 255) / 256;    // 12500

    hipMemsetAsync(cnt, 0, (size_t)N_NODES * sizeof(int), stream);

    prep_kernel<<<castblocks + bpart, 256, 0, stream>>>(x, casth, total4, dst, cnt, gh,
                                                        E, bpart, castblocks);
    scanA_kernel<<<SCAN_BLOCKS + blocksB, 256, 0, stream>>>(cnt, offs, partialA, gh, partialB, n, m);
    scanB_kernel<<<2, 512, 0, stream>>>(partialA, SCAN_BLOCKS, partialB, blocksB);
    scanC_kernel<<<SCAN_BLOCKS + blocksB, 256, 0, stream>>>(offs, partialA, gh, partialB, n, m);

    phase2_kernel<<<bpart, 256, 0, stream>>>(src, dst, gh, pairs, E, bpart);
    phase3_kernel<<<NBUCK, 256, 0, stream>>>(pairs, gh, offs, esrc, E, bpart, n);

    const int aggb = (n * 64 + 255) / 256;
    const int gemmb = (n + 127) / 128;

    // layer 1: agg(x_h) -> aggh; h = relu(normalize(aggh@W1l^T + b1 + x_h@W1r^T)) -> fp16 aggh
    aggregate_kernel<<<aggb, 256, 0, stream>>>(casth, esrc, offs, cnt, aggh, n);
    gemm_mfma_kernel<true><<<gemmb, 256, 0, stream>>>(aggh, casth, W1l, W1r, b1, nullptr, aggh, n);

    // layer 2: agg(h) -> casth; out = casth@W2l^T + b2 + h@W2r^T (fp32 to d_out)
    aggregate_kernel<<<aggb, 256, 0, stream>>>(aggh, esrc, offs, cnt, casth, n);
    gemm_mfma_kernel<false><<<gemmb, 256, 0, stream>>>(casth, aggh, W2l, W2r, b2, out, nullptr, n);
}

// Round 6
// 381.985 us; speedup vs baseline: 1.7491x; 1.2052x over previous
//
#include <hip/hip_runtime.h>
#include <hip/hip_bf16.h>
#include <hip/hip_fp16.h>

#define N_NODES 100000
#define DFEAT 128
#define SLAB 4096         // edges per partition block
#define BSHIFT 9          // 512 nodes per bucket
#define NBUCK 196         // ceil(100000/512)

// ---------------- ws layout (4-byte units) ----------------
// cnt    [0      , 100000)   written by phase3 (no memset needed)
// gh     [100000 , 176636)   bucket-major (bucket,block) histogram -> scanned bases
// partialB[180000, 180512)
// offs   [200000 , 300096)   written by phase3
// esrc   [300608 , 1900608)
// aggh   [1900608, 8300608)   first: int2 pairs buffer; then fp16 agg1 / h
// casth  [8300608, 14700608)  fp16 x_h, then agg2
#define WS_CNT      0
#define WS_GH       100000
#define WS_PARTB    180000
#define WS_OFFS     200000
#define WS_ESRC     300608
#define WS_AGGH     1900608
#define WS_CASTH    8300608

typedef _Float16 half8 __attribute__((ext_vector_type(8)));
typedef _Float16 half2v __attribute__((ext_vector_type(2)));
typedef float floatx4 __attribute__((ext_vector_type(4)));

// ---------- fused prep: cast x->fp16 (blocks < castblocks) + slab bucket hist ----------
// NO global atomics: per-node degree is derived later in phase3.
__global__ __launch_bounds__(256) void prep_kernel(const float* __restrict__ x,
                                                   __half* __restrict__ xh, int total4,
                                                   const int* __restrict__ dst,
                                                   int* __restrict__ gh,
                                                   int E, int bpart, int castblocks) {
    __shared__ int lh[NBUCK];
    int b = blockIdx.x;
    if (b < castblocks) {
        int i = b * 256 + threadIdx.x;
        if (i < total4) {
            float4 v = ((const float4*)x)[i];
            __half2 h01 = __floats2half2_rn(v.x, v.y);
            __half2 h23 = __floats2half2_rn(v.z, v.w);
            uint2 o;
            o.x = *(unsigned int*)&h01;
            o.y = *(unsigned int*)&h23;
            ((uint2*)xh)[i] = o;
        }
        return;
    }
    int bb = b - castblocks;
    for (int i = threadIdx.x; i < NBUCK; i += 256) lh[i] = 0;
    __syncthreads();
    int s0 = bb * SLAB, s1 = min(E, s0 + SLAB);
    for (int i = s0 + threadIdx.x; i < s1; i += 256)
        atomicAdd(&lh[dst[i] >> BSHIFT], 1);
    __syncthreads();
    for (int i = threadIdx.x; i < NBUCK; i += 256) gh[i * bpart + bb] = lh[i];
}

// ---------- exclusive-scan trio over gh (in-place) ----------
__global__ void scan1_kernel(int* __restrict__ gh, int* __restrict__ partial, int m) {
    __shared__ int s[256];
    int i = blockIdx.x * 256 + threadIdx.x;
    int v = (i < m) ? gh[i] : 0;
    s[threadIdx.x] = v;
    __syncthreads();
    for (int d = 1; d < 256; d <<= 1) {
        int t = (threadIdx.x >= d) ? s[threadIdx.x - d] : 0;
        __syncthreads();
        s[threadIdx.x] += t;
        __syncthreads();
    }
    int incl = s[threadIdx.x];
    if (i < m) gh[i] = incl - v;
    if (threadIdx.x == 255) partial[blockIdx.x] = incl;
}

__global__ void scan2_kernel(int* __restrict__ partial, int nb) {
    __shared__ int s[512];
    int t = threadIdx.x;
    int v = (t < nb) ? partial[t] : 0;
    s[t] = v;
    __syncthreads();
    for (int d = 1; d < 512; d <<= 1) {
        int u = (t >= d) ? s[t - d] : 0;
        __syncthreads();
        s[t] += u;
        __syncthreads();
    }
    if (t < nb) partial[t] = s[t] - v;
}

__global__ void scan3_kernel(int* __restrict__ gh, const int* __restrict__ partial, int m) {
    int i = blockIdx.x * 256 + threadIdx.x;
    if (i < m) gh[i] += partial[blockIdx.x];
}

// ---------- phase 2: LDS counting-sort slab by bucket, copy runs out ----------
__global__ __launch_bounds__(256) void phase2_kernel(const int* __restrict__ src,
                                                     const int* __restrict__ dst,
                                                     const int* __restrict__ gbase,
                                                     int2* __restrict__ pairs,
                                                     int E, int bpart) {
    __shared__ int lbase[NBUCK];
    __shared__ int lcur[NBUCK];
    __shared__ int lgb[NBUCK];
    __shared__ int sc[256];
    __shared__ int2 lp[SLAB];   // 32 KB
    int b = blockIdx.x;
    int t = threadIdx.x;
    for (int i = t; i < NBUCK; i += 256) lbase[i] = 0;
    __syncthreads();
    int s0 = b * SLAB, s1 = min(E, s0 + SLAB);
    for (int i = s0 + t; i < s1; i += 256)
        atomicAdd(&lbase[dst[i] >> BSHIFT], 1);
    __syncthreads();
    int v = (t < NBUCK) ? lbase[t] : 0;
    sc[t] = v;
    __syncthreads();
    for (int d = 1; d < 256; d <<= 1) {
        int u = (t >= d) ? sc[t - d] : 0;
        __syncthreads();
        sc[t] += u;
        __syncthreads();
    }
    if (t < NBUCK) {
        int excl = sc[t] - v;
        lbase[t] = excl;
        lcur[t] = excl;
        lgb[t] = gbase[t * bpart + b];
    }
    __syncthreads();
    for (int i = s0 + t; i < s1; i += 256) {
        int d = dst[i];
        int s = src[i];
        int bk = d >> BSHIFT;
        int pos = atomicAdd(&lcur[bk], 1);
        lp[pos] = make_int2(s, d);
    }
    __syncthreads();
    int m = s1 - s0;
    for (int i = t; i < m; i += 256) {
        int2 p = lp[i];
        int bk = p.y >> BSHIFT;
        pairs[lgb[bk] + (i - lbase[bk])] = p;
    }
}

// ---------- phase 3: per-bucket node hist (LDS) + scan -> cnt/offs + CSR finalize ----------
__global__ __launch_bounds__(512) void phase3_kernel(const int2* __restrict__ pairs,
                                                     const int* __restrict__ gbase,
                                                     int* __restrict__ cnt,
                                                     int* __restrict__ offs,
                                                     int* __restrict__ esrc,
                                                     int E, int bpart, int n) {
    __shared__ int lcnt[512];
    __shared__ int sc[512];
    __shared__ int lexcl[512];
    int g = blockIdx.x;
    int node0 = g << BSHIFT;
    int t = threadIdx.x;
    lcnt[t] = 0;
    __syncthreads();
    int S = gbase[g * bpart];
    int Eg = (g == NBUCK - 1) ? E : gbase[(g + 1) * bpart];
    // pass 1: count per node (LDS atomics)
    for (int i = S + t; i < Eg; i += 512)
        atomicAdd(&lcnt[pairs[i].y - node0], 1);
    __syncthreads();
    // exclusive scan of 512 counters
    int v = lcnt[t];
    sc[t] = v;
    __syncthreads();
    for (int d = 1; d < 512; d <<= 1) {
        int u = (t >= d) ? sc[t - d] : 0;
        __syncthreads();
        sc[t] += u;
        __syncthreads();
    }
    int excl = sc[t] - v;
    lexcl[t] = excl;
    int nd = node0 + t;
    if (nd < n) {
        cnt[nd] = v;
        offs[nd] = S + excl;
    }
    __syncthreads();
    // pass 2: place edges; lexcl doubles as cursor (old value = slot in bucket)
    for (int i = S + t; i < Eg; i += 512) {
        int2 p = pairs[i];
        int pos = atomicAdd(&lexcl[p.y - node0], 1);
        esrc[S + pos] = p.x;
    }
}

// ---------- aggregate: one wave per node, packed-fp16 accumulate ----------
__global__ void aggregate_kernel(const __half* __restrict__ feat, const int* __restrict__ esrc,
                                 const int* __restrict__ offs, const int* __restrict__ cnt,
                                 __half* __restrict__ agg, int n) {
    int wid = (blockIdx.x * blockDim.x + threadIdx.x) >> 6;
    int lane = threadIdx.x & 63;
    if (wid >= n) return;
    int beg = offs[wid];
    int deg = cnt[wid];
    int half_id = lane >> 5;
    int colbase = (lane & 31) * 4;
    half2v s01 = (half2v)(_Float16)0;
    half2v s23 = (half2v)(_Float16)0;

    for (int base = 0; base < deg; base += 64) {
        int m = min(64, deg - base);
        int idx = (lane < m) ? esrc[beg + base + lane] : 0;
#pragma unroll 8
        for (int j = 0; j < m; j += 2) {
            int jj = j + half_id;
            bool valid = jj < m;
            int s = __shfl(idx, valid ? jj : (m - 1));
            uint2 raw = *(const uint2*)(feat + (size_t)s * DFEAT + colbase);
            if (!valid) { raw.x = 0u; raw.y = 0u; }
            s01 += *(half2v*)&raw.x;
            s23 += *(half2v*)&raw.y;
        }
    }
    float a0 = (float)s01.x, a1 = (float)s01.y;
    float a2 = (float)s23.x, a3 = (float)s23.y;
    a0 += __shfl_xor(a0, 32);
    a1 += __shfl_xor(a1, 32);
    a2 += __shfl_xor(a2, 32);
    a3 += __shfl_xor(a3, 32);

    if (lane < 32) {
        float scale = 1.0f / fmaxf((float)deg, 1.0f);
        __half2 h01 = __floats2half2_rn(a0 * scale, a1 * scale);
        __half2 h23 = __floats2half2_rn(a2 * scale, a3 * scale);
        uint2 o;
        o.x = *(unsigned int*)&h01;
        o.y = *(unsigned int*)&h23;
        *(uint2*)(agg + (size_t)wid * DFEAT + colbase) = o;
    }
}

// ---------- MFMA dual-GEMM, LDS-staged weights, D[feat][node] orientation ----------
template <bool NORM_RELU>
__global__ __launch_bounds__(256) void gemm_mfma_kernel(
    const __half* __restrict__ A1_, const __half* __restrict__ A2_,
    const float* __restrict__ Wl, const float* __restrict__ Wr,
    const float* __restrict__ bias, float* __restrict__ out32,
    __half* __restrict__ out16, int n) {
    __shared__ __align__(16) _Float16 lw[128 * 136];   // 34.8 KB

    const _Float16* A1 = (const _Float16*)A1_;
    const _Float16* A2 = (const _Float16*)A2_;

    const int lane = threadIdx.x & 63;
    const int w = threadIdx.x >> 6;       // wave 0..3
    const int quad = lane >> 4;           // 0..3
    const int l15 = lane & 15;
    const int i0 = blockIdx.x * 128 + w * 32;   // wave's first node row

    floatx4 acc[2][8];
#pragma unroll
    for (int nt = 0; nt < 2; nt++)
#pragma unroll
        for (int ft = 0; ft < 8; ft++)
            acc[nt][ft] = (floatx4){0.f, 0.f, 0.f, 0.f};

    int r0 = i0 + l15;      if (r0 >= n) r0 = n - 1;
    int r1 = i0 + 16 + l15; if (r1 >= n) r1 = n - 1;
    const int kq = quad * 8;

    for (int half = 0; half < 2; half++) {
        const float* __restrict__ W = half ? Wr : Wl;
        const _Float16* __restrict__ A = half ? A2 : A1;
        if (half) __syncthreads();
        {
            int t = threadIdx.x;
            int row = t >> 1;
            int cb = (t & 1) * 64;
            const float4* sp = (const float4*)(W + row * DFEAT + cb);
            unsigned int* dp = (unsigned int*)&lw[row * 136 + cb];
#pragma unroll
            for (int q = 0; q < 16; q++) {
                float4 v = sp[q];
                __half2 h01 = __floats2half2_rn(v.x, v.y);
                __half2 h23 = __floats2half2_rn(v.z, v.w);
                dp[q * 2] = *(unsigned int*)&h01;
                dp[q * 2 + 1] = *(unsigned int*)&h23;
            }
        }
        __syncthreads();
#pragma unroll
        for (int kc = 0; kc < DFEAT; kc += 32) {
            half8 b0 = *(const half8*)(A + (size_t)r0 * DFEAT + kc + kq);
            half8 b1 = *(const half8*)(A + (size_t)r1 * DFEAT + kc + kq);
#pragma unroll
            for (int ft = 0; ft < 8; ft++) {
                half8 a = *(const half8*)&lw[(ft * 16 + l15) * 136 + kc + kq];
                acc[0][ft] = __builtin_amdgcn_mfma_f32_16x16x32_f16(a, b0, acc[0][ft], 0, 0, 0);
                acc[1][ft] = __builtin_amdgcn_mfma_f32_16x16x32_f16(a, b1, acc[1][ft], 0, 0, 0);
            }
        }
    }

#pragma unroll
    for (int nt = 0; nt < 2; nt++) {
        int node = i0 + nt * 16 + l15;
        float v[8][4];
#pragma unroll
        for (int ft = 0; ft < 8; ft++) {
            const float4 bq = *(const float4*)(bias + ft * 16 + quad * 4);
            v[ft][0] = acc[nt][ft][0] + bq.x;
            v[ft][1] = acc[nt][ft][1] + bq.y;
            v[ft][2] = acc[nt][ft][2] + bq.z;
            v[ft][3] = acc[nt][ft][3] + bq.w;
        }
        if (NORM_RELU) {
            float ss = 0.f;
#pragma unroll
            for (int ft = 0; ft < 8; ft++)
#pragma unroll
                for (int r = 0; r < 4; r++) ss = fmaf(v[ft][r], v[ft][r], ss);
            ss += __shfl_xor(ss, 16);
            ss += __shfl_xor(ss, 32);
            float inv = 1.0f / fmaxf(sqrtf(ss), 1e-12f);
#pragma unroll
            for (int ft = 0; ft < 8; ft++)
#pragma unroll
                for (int r = 0; r < 4; r++) v[ft][r] = fmaxf(v[ft][r] * inv, 0.0f);
        }
        if (node < n) {
            if (NORM_RELU) {
                __half* op = (__half*)out16 + (size_t)node * DFEAT + quad * 4;
#pragma unroll
                for (int ft = 0; ft < 8; ft++) {
                    __half2 h01 = __floats2half2_rn(v[ft][0], v[ft][1]);
                    __half2 h23 = __floats2half2_rn(v[ft][2], v[ft][3]);
                    uint2 o;
                    o.x = *(unsigned int*)&h01;
                    o.y = *(unsigned int*)&h23;
                    *(uint2*)(op + ft * 16) = o;
                }
            } else {
                float* op = out32 + (size_t)node * DFEAT + quad * 4;
#pragma unroll
                for (int ft = 0; ft < 8; ft++)
                    *(float4*)(op + ft * 16) = make_float4(v[ft][0], v[ft][1], v[ft][2], v[ft][3]);
            }
        }
    }
}

extern "C" void kernel_launch(void* const* d_in, const int* in_sizes, int n_in,
                              void* d_out, int out_size, void* d_ws, size_t ws_size,
                              hipStream_t stream) {
    const float* x = (const float*)d_in[0];
    const int* edge_index = (const int*)d_in[1];
    const float* W1l = (const float*)d_in[2];
    const float* b1 = (const float*)d_in[3];
    const float* W1r = (const float*)d_in[4];
    const float* W2l = (const float*)d_in[5];
    const float* b2 = (const float*)d_in[6];
    const float* W2r = (const float*)d_in[7];
    float* out = (float*)d_out;

    const int E = in_sizes[1] / 2;
    const int n = in_sizes[0] / DFEAT;  // 100000

    int* ws = (int*)d_ws;
    int* cnt = ws + WS_CNT;
    int* gh = ws + WS_GH;
    int* partialB = ws + WS_PARTB;
    int* offs = ws + WS_OFFS;
    int* esrc = ws + WS_ESRC;
    int2* pairs = (int2*)(ws + WS_AGGH);
    __half* aggh = (__half*)(ws + WS_AGGH);
    __half* casth = (__half*)(ws + WS_CASTH);

    const int* src = edge_index;
    const int* dst = edge_index + E;

    const int bpart = (E + SLAB - 1) / SLAB;        // 391
    const int m = NBUCK * bpart;                    // 76636
    const int blocksB = (m + 255) / 256;            // 300
    const int total4 = n * DFEAT / 4;
    const int castblocks = (total4 + 255) / 256;    // 12500

    prep_kernel<<<castblocks + bpart, 256, 0, stream>>>(x, casth, total4, dst, gh,
                                                        E, bpart, castblocks);
    scan1_kernel<<<blocksB, 256, 0, stream>>>(gh, partialB, m);
    scan2_kernel<<<1, 512, 0, stream>>>(partialB, blocksB);
    scan3_kernel<<<blocksB, 256, 0, stream>>>(gh, partialB, m);

    phase2_kernel<<<bpart, 256, 0, stream>>>(src, dst, gh, pairs, E, bpart);
    phase3_kernel<<<NBUCK, 512, 0, stream>>>(pairs, gh, cnt, offs, esrc, E, bpart, n);

    const int aggb = (n * 64 + 255) / 256;
    const int gemmb = (n + 127) / 128;

    // layer 1: agg(x_h) -> aggh; h = relu(normalize(aggh@W1l^T + b1 + x_h@W1r^T)) -> fp16 aggh
    aggregate_kernel<<<aggb, 256, 0, stream>>>(casth, esrc, offs, cnt, aggh, n);
    gemm_mfma_kernel<true><<<gemmb, 256, 0, stream>>>(aggh, casth, W1l, W1r, b1, nullptr, aggh, n);

    // layer 2: agg(h) -> casth; out = casth@W2l^T + b2 + h@W2r^T (fp32 to d_out)
    aggregate_kernel<<<aggb, 256, 0, stream>>>(aggh, esrc, offs, cnt, casth, n);
    gemm_mfma_kernel<false><<<gemmb, 256, 0, stream>>>(casth, aggh, W2l, W2r, b2, out, nullptr, n);
}